// Round 3
// baseline (727.240 us; speedup 1.0000x reference)
//
#include <hip/hip_runtime.h>
#include <hip/hip_bf16.h>

typedef unsigned int   u32;
typedef unsigned short u16;
typedef _Float16       f16;
typedef __attribute__((ext_vector_type(8))) _Float16 f16x8;
typedef __attribute__((ext_vector_type(4))) float    f32x4;

#define T_STEPS 512
#define BATCH   256
#define O_IN    720
#define KPAD    736      // 720 padded to mult of 32 (zero pad in wxt)
#define HID     128
#define G4      512      // 4*HID
// d_out layout (floats): am[512] | std[2] | value[256] | hT[32768] | cT[32768]
#define OUT_STD 512
#define OUT_VAL 514
#define OUT_HT  770
#define OUT_CT  33538

// ws layout (bytes); requires ws_size >= ~135 MB
static const unsigned long long XW_OFF  = 0ull;          // f16 [131072][512] = 134217728 B
static const unsigned long long WXT_OFF = 134217728ull;  // f16 [512][736]    = 753664 B

__device__ inline float exp2fast(float x){
#if __has_builtin(__builtin_amdgcn_exp2f)
  return __builtin_amdgcn_exp2f(x);
#else
  return exp2f(x);
#endif
}
__device__ inline float sigf(float x){ return 1.0f / (1.0f + exp2fast(-1.44269504f * x)); }
__device__ inline float tanhfast(float x){ return 2.0f / (1.0f + exp2fast(-2.88539008f * x)) - 1.0f; }

// ---------------- K0: Wx (720,512) f32 -> Wx^T f16 [512][736] zero-padded ----------------
__global__ void k_pack_wxt(const float* __restrict__ Wx, u16* __restrict__ wxt){
  const int n = blockIdx.x;               // 512 blocks
  for (int k = threadIdx.x; k < KPAD; k += 256){
    float v = (k < O_IN) ? Wx[(size_t)k * G4 + n] : 0.f;
    wxt[(size_t)n * KPAD + k] = __builtin_bit_cast(u16, (f16)v);
  }
}

// ---------------- K1: xW = x @ Wx  (fp16 MFMA, LDS-free, no barriers) --------------------
// grid 2048: WG tile 256x128 (4 waves of 64x128), K = 22*32 full + 16 tail.
// Validated by outputs 0-2 passing in R1/R2 (xw feeds everything downstream).
__global__ __launch_bounds__(256, 2) void k_gemm(const float* __restrict__ x,
                                                 const u16* __restrict__ wxt,
                                                 u16* __restrict__ xw)
{
  const int l  = threadIdx.x & 63;
  const int w  = threadIdx.x >> 6;
  const int lr = l & 15;        // A row / B col / D col
  const int lk = l >> 4;        // k-group (8 k each), lk in [0,4)
  // XCD-chunked swizzle (bijective: 2048 = 8*256)
  const u32 L  = (blockIdx.x & 7u) * 256u + (blockIdx.x >> 3);
  const u32 mb = L >> 2, nb = L & 3u;
  const u32 M0 = mb * 256u + (u32)w * 64u;
  const u32 N0 = nb * 128u;

  const float* ax[4];
  const u16*   bx[8];
#pragma unroll
  for (int mf = 0; mf < 4; ++mf)
    ax[mf] = x + (unsigned long long)(M0 + mf*16 + lr) * O_IN + lk*8;
#pragma unroll
  for (int nf = 0; nf < 8; ++nf)
    bx[nf] = wxt + (unsigned long long)(N0 + nf*16 + lr) * KPAD + lk*8;

  f32x4 acc[4][8];
#pragma unroll
  for (int mf = 0; mf < 4; ++mf)
#pragma unroll
    for (int nf = 0; nf < 8; ++nf)
      acc[mf][nf] = (f32x4){0.f, 0.f, 0.f, 0.f};

  f32x4 a0[4][2];
  f16x8 aF[4], bF[8];

#pragma unroll
  for (int mf = 0; mf < 4; ++mf){
    a0[mf][0] = *(const f32x4*)(ax[mf]);
    a0[mf][1] = *(const f32x4*)(ax[mf] + 4);
  }
#pragma unroll
  for (int nf = 0; nf < 8; ++nf)
    bF[nf] = *(const f16x8*)(bx[nf]);
#pragma unroll
  for (int mf = 0; mf < 4; ++mf){
    f32x4 lo = a0[mf][0], hi = a0[mf][1];
    f16x8 v; v[0]=(f16)lo.x; v[1]=(f16)lo.y; v[2]=(f16)lo.z; v[3]=(f16)lo.w;
             v[4]=(f16)hi.x; v[5]=(f16)hi.y; v[6]=(f16)hi.z; v[7]=(f16)hi.w;
    aF[mf] = v;
  }

  for (int kc = 0; kc < 22; ++kc){
    if (kc < 21){                               // issue next A (long-latency) early
#pragma unroll
      for (int mf = 0; mf < 4; ++mf){
        a0[mf][0] = *(const f32x4*)(ax[mf] + (kc+1)*32);
        a0[mf][1] = *(const f32x4*)(ax[mf] + (kc+1)*32 + 4);
      }
    }
#pragma unroll
    for (int nf = 0; nf < 8; ++nf){
#pragma unroll
      for (int mf = 0; mf < 4; ++mf)
        acc[mf][nf] = __builtin_amdgcn_mfma_f32_16x16x32_f16(aF[mf], bF[nf], acc[mf][nf], 0, 0, 0);
      if (kc < 21)                              // reload B right after last use (L2-hit)
        bF[nf] = *(const f16x8*)(bx[nf] + (kc+1)*32);
    }
    if (kc < 21){
#pragma unroll
      for (int mf = 0; mf < 4; ++mf){
        f32x4 lo = a0[mf][0], hi = a0[mf][1];
        f16x8 v; v[0]=(f16)lo.x; v[1]=(f16)lo.y; v[2]=(f16)lo.z; v[3]=(f16)lo.w;
                 v[4]=(f16)hi.x; v[5]=(f16)hi.y; v[6]=(f16)hi.z; v[7]=(f16)hi.w;
        aF[mf] = v;
      }
    }
  }

  { // K tail: k = 704..719 valid (lanes lk<2), wxt zero-padded to 736
    f16x8 aT[4];
#pragma unroll
    for (int mf = 0; mf < 4; ++mf) aT[mf] = (f16x8)(f16)0.f;
    if (lk < 2){
#pragma unroll
      for (int mf = 0; mf < 4; ++mf){
        f32x4 lo = *(const f32x4*)(ax[mf] + 704);
        f32x4 hi = *(const f32x4*)(ax[mf] + 708);
        f16x8 v; v[0]=(f16)lo.x; v[1]=(f16)lo.y; v[2]=(f16)lo.z; v[3]=(f16)lo.w;
                 v[4]=(f16)hi.x; v[5]=(f16)hi.y; v[6]=(f16)hi.z; v[7]=(f16)hi.w;
        aT[mf] = v;
      }
    }
#pragma unroll
    for (int nf = 0; nf < 8; ++nf){
      f16x8 bT = *(const f16x8*)(bx[nf] + 704);
#pragma unroll
      for (int mf = 0; mf < 4; ++mf)
        acc[mf][nf] = __builtin_amdgcn_mfma_f32_16x16x32_f16(aT[mf], bT, acc[mf][nf], 0, 0, 0);
    }
  }

  // epilogue: D row = lk*4 + r, col = lr
#pragma unroll
  for (int mf = 0; mf < 4; ++mf){
    const u32 rowb = M0 + mf*16 + lk*4;
#pragma unroll
    for (int nf = 0; nf < 8; ++nf){
      const u32 col = N0 + nf*16 + lr;
#pragma unroll
      for (int r = 0; r < 4; ++r)
        xw[(unsigned long long)(rowb + r) * G4 + col] = __builtin_bit_cast(u16, (f16)acc[mf][nf][r]);
    }
  }
}

// ---------------- K2: LSTM scan, FULL FP32 recurrence (1 batch row/WG, 512 thr) -----------
// Thread t owns gate col t. Wh col t = 128 fp32 VGPRs (fully-unrolled static indexing).
// h kept fp32 in LDS (no per-step rounding). Only noise source: fp16 xW input.
__global__ __launch_bounds__(512) void k_rnn(
    const u16* __restrict__ xw, const float* __restrict__ Wh,
    const float* __restrict__ h0, const float* __restrict__ c0,
    const float* __restrict__ bvec,
    const float* __restrict__ Wa1, const float* __restrict__ ba1,
    const float* __restrict__ Wa2, const float* __restrict__ ba2,
    const float* __restrict__ Wc1, const float* __restrict__ bc1,
    const float* __restrict__ Wc2, const float* __restrict__ bc2,
    const float* __restrict__ log_std, float* __restrict__ out)
{
  const int b = blockIdx.x;
  const int t = threadIdx.x;          // 0..511

  __shared__ __align__(16) float hf[HID];   // h, fp32
  __shared__ float act[G4];
  __shared__ float hid[256];

  float w[HID];                        // Wh column t, fp32, fully static
#pragma unroll
  for (int k = 0; k < HID; ++k)
    w[k] = Wh[(u32)k * G4 + t];
  const float bb = bvec[t];

  float cs = 0.f, hv = 0.f;
  if (t < HID){
    hv = h0[b*HID + t];
    cs = c0[b*HID + t];
    hf[t] = hv;
  }
  __syncthreads();

  const u16* xp = xw + (u32)b * G4 + t;     // stride/step: 256*512 elems
  u16 xcur = xp[0];
  const bool is_g = ((t >> 7) == 2);        // gate region g (wave-uniform)
  const f32x4* hp4 = (const f32x4*)hf;

  for (int s = 0; s < T_STEPS; ++s){
    u16 xnext = 0;
    if (s + 1 < T_STEPS) xnext = xp[(u32)(s+1) * 131072u];   // prefetch

    float s0 = 0.f, s1 = 0.f, s2 = 0.f, s3 = 0.f;            // 4 parallel chains
#pragma unroll
    for (int q = 0; q < 32; ++q){
      f32x4 hh = hp4[q];                   // broadcast ds_read_b128
      s0 = fmaf(hh.x, w[4*q+0], s0);
      s1 = fmaf(hh.y, w[4*q+1], s1);
      s2 = fmaf(hh.z, w[4*q+2], s2);
      s3 = fmaf(hh.w, w[4*q+3], s3);
    }
    float g = (float)__builtin_bit_cast(f16, xcur) + bb + ((s0 + s1) + (s2 + s3));
    act[t] = is_g ? tanhfast(g) : sigf(g);
    __syncthreads();
    if (t < HID){                          // combine gates, update c,h (fp32)
      float gi = act[t], gf = act[t + 128], gg = act[t + 256], go = act[t + 384];
      cs = gf * cs + gi * gg;
      hv = go * tanhfast(cs);
      hf[t] = hv;
    }
    __syncthreads();
    xcur = xnext;
  }

  if (t < HID){                            // hT, cT exact fp32 state
    out[OUT_HT + b*HID + t] = hv;
    out[OUT_CT + b*HID + t] = cs;
  }

  if (t < 256){ // heads hidden, fp32: t<128 -> actor col t; else critic col t-128
    const float* W = (t < HID) ? Wa1 : Wc1;
    const int col  = t & (HID - 1);
    float a0 = 0.f, a1 = 0.f, a2 = 0.f, a3 = 0.f;
#pragma unroll
    for (int q = 0; q < 32; ++q){
      f32x4 hh = hp4[q];
      a0 = fmaf(hh.x, W[(u32)(4*q+0)*HID + col], a0);
      a1 = fmaf(hh.y, W[(u32)(4*q+1)*HID + col], a1);
      a2 = fmaf(hh.z, W[(u32)(4*q+2)*HID + col], a2);
      a3 = fmaf(hh.w, W[(u32)(4*q+3)*HID + col], a3);
    }
    float a = (a0 + a1) + (a2 + a3);
    hid[t] = (t < HID) ? tanhfast(a + ba1[col]) : tanhfast(a + bc1[col]);
  }
  __syncthreads();

  {
    const int wv = t >> 6, lane = t & 63;
    float p = 0.f;
    if (wv == 0)      p = hid[lane]     * Wa2[lane*2]   + hid[lane+64]     * Wa2[(lane+64)*2];
    else if (wv == 1) p = hid[lane]     * Wa2[lane*2+1] + hid[lane+64]     * Wa2[(lane+64)*2+1];
    else if (wv == 2) p = hid[128+lane] * Wc2[lane]     + hid[128+lane+64] * Wc2[lane+64];
#pragma unroll
    for (int off = 32; off > 0; off >>= 1) p += __shfl_down(p, off);
    if (lane == 0){
      if (wv == 0) out[b*2 + 0]   = p + ba2[0];
      if (wv == 1) out[b*2 + 1]   = p + ba2[1];
      if (wv == 2) out[OUT_VAL+b] = p + bc2[0];
    }
    if (b == 0 && wv == 3 && lane < 2) out[OUT_STD + lane] = expf(log_std[lane]);
  }
}

extern "C" void kernel_launch(void* const* d_in, const int* in_sizes, int n_in,
                              void* d_out, int out_size, void* d_ws, size_t ws_size,
                              hipStream_t stream)
{
  (void)in_sizes; (void)n_in; (void)out_size; (void)ws_size;
  const float* x    = (const float*)d_in[0];
  const float* h0   = (const float*)d_in[1];
  const float* c0   = (const float*)d_in[2];
  const float* Wx   = (const float*)d_in[3];
  const float* Wh   = (const float*)d_in[4];
  const float* bv   = (const float*)d_in[5];
  const float* Wa1  = (const float*)d_in[6];
  const float* ba1  = (const float*)d_in[7];
  const float* Wa2  = (const float*)d_in[8];
  const float* ba2  = (const float*)d_in[9];
  const float* lstd = (const float*)d_in[10];
  const float* Wc1  = (const float*)d_in[11];
  const float* bc1  = (const float*)d_in[12];
  const float* Wc2  = (const float*)d_in[13];
  const float* bc2  = (const float*)d_in[14];
  float* out = (float*)d_out;
  char*  ws  = (char*)d_ws;

  u16* xw  = (u16*)(ws + XW_OFF);
  u16* wxt = (u16*)(ws + WXT_OFF);

  k_pack_wxt<<<dim3(512),  dim3(256), 0, stream>>>(Wx, wxt);
  k_gemm<<<dim3(2048),     dim3(256), 0, stream>>>(x, wxt, xw);
  k_rnn<<<dim3(256),       dim3(512), 0, stream>>>(xw, Wh, h0, c0, bv,
                                                   Wa1, ba1, Wa2, ba2, Wc1, bc1, Wc2, bc2,
                                                   lstd, out);
}